// Round 1
// baseline (1171.922 us; speedup 1.0000x reference)
//
#include <hip/hip_runtime.h>

#define NN 50000
#define NE 800000
#define NG 512
#define TPB 256
#define BN_EPS 1e-5f

__global__ void k_zero(float* __restrict__ p, int n) {
  int i = blockIdx.x * TPB + threadIdx.x;
  if (i < n) p[i] = 0.f;
}

// h[n][0:64] = emb[x[n]][0:64], processed as float4 (16 per row)
__global__ void k_embed(const int* __restrict__ x, const float* __restrict__ emb,
                        float* __restrict__ h) {
  int i = blockIdx.x * TPB + threadIdx.x;
  if (i >= NN * 16) return;
  ((float4*)h)[i] = ((const float4*)emb)[x[i >> 4] * 16 + (i & 15)];
}

__global__ void k_hist(const int* __restrict__ dst, int* __restrict__ counts) {
  int e = blockIdx.x * TPB + threadIdx.x;
  if (e < NE) atomicAdd(&counts[dst[e]], 1);
}

// per-block inclusive scan of counts -> incl, block totals -> btot
__global__ void k_scan1(const int* __restrict__ counts, int* __restrict__ incl,
                        int* __restrict__ btot) {
  __shared__ int lds[TPB];
  int i = blockIdx.x * TPB + threadIdx.x;
  int v = (i < NN) ? counts[i] : 0;
  lds[threadIdx.x] = v;
  __syncthreads();
  for (int off = 1; off < TPB; off <<= 1) {
    int t = (threadIdx.x >= off) ? lds[threadIdx.x - off] : 0;
    __syncthreads();
    lds[threadIdx.x] += t;
    __syncthreads();
  }
  if (i < NN) incl[i] = lds[threadIdx.x];
  if (threadIdx.x == TPB - 1) btot[blockIdx.x] = lds[TPB - 1];
}

// exclusive scan of btot in place (nb <= 256, single block)
__global__ void k_scan2(int* __restrict__ btot, int nb) {
  __shared__ int lds[TPB];
  int t = (threadIdx.x < nb) ? btot[threadIdx.x] : 0;
  int own = t;
  lds[threadIdx.x] = t;
  __syncthreads();
  for (int off = 1; off < TPB; off <<= 1) {
    int u = (threadIdx.x >= off) ? lds[threadIdx.x - off] : 0;
    __syncthreads();
    lds[threadIdx.x] += u;
    __syncthreads();
  }
  btot[threadIdx.x] = lds[threadIdx.x] - own;
}

__global__ void k_scan3(const int* __restrict__ incl, const int* __restrict__ btot,
                        int* __restrict__ row_ptr) {
  int i = blockIdx.x * TPB + threadIdx.x;
  if (i == 0) row_ptr[0] = 0;
  if (i < NN) row_ptr[i + 1] = incl[i] + btot[i >> 8];
}

__global__ void k_fill(const int* __restrict__ src, const int* __restrict__ dst,
                       const int* __restrict__ row_ptr, int* __restrict__ fill_pos,
                       int* __restrict__ srcs) {
  int e = blockIdx.x * TPB + threadIdx.x;
  if (e >= NE) return;
  int d = dst[e];
  int pos = row_ptr[d] + atomicAdd(&fill_pos[d], 1);
  srcs[pos] = src[e];
}

// z[n] = h[n] + sum_{e in csr(n)} h[srcs[e]] ; one wave per node, lane = feature
__global__ void k_aggregate(const float* __restrict__ h, const int* __restrict__ row_ptr,
                            const int* __restrict__ srcs, float* __restrict__ z) {
  int wid = (blockIdx.x * TPB + threadIdx.x) >> 6;
  int lane = threadIdx.x & 63;
  if (wid >= NN) return;
  int beg = row_ptr[wid], end = row_ptr[wid + 1];
  float acc = h[wid * 64 + lane];
  int e = beg;
  for (; e + 4 <= end; e += 4) {
    int s0 = srcs[e], s1 = srcs[e + 1], s2 = srcs[e + 2], s3 = srcs[e + 3];
    float v0 = h[s0 * 64 + lane], v1 = h[s1 * 64 + lane];
    float v2 = h[s2 * 64 + lane], v3 = h[s3 * 64 + lane];
    acc += v0 + v1 + v2 + v3;
  }
  for (; e < end; ++e) acc += h[srcs[e] * 64 + lane];
  z[wid * 64 + lane] = acc;
}

// z2[N,128] = z[N,64] @ W[64,128] + bias ; row per thread, W in LDS
__global__ __launch_bounds__(TPB) void k_gemm1(const float* __restrict__ z,
                                               const float* __restrict__ W,
                                               const float* __restrict__ bias,
                                               float* __restrict__ z2) {
  __shared__ float Wl[64 * 128];
  __shared__ float bl[128];
  for (int t = threadIdx.x; t < 64 * 128 / 4; t += TPB)
    ((float4*)Wl)[t] = ((const float4*)W)[t];
  if (threadIdx.x < 128) bl[threadIdx.x] = bias[threadIdx.x];
  __syncthreads();
  int r = blockIdx.x * TPB + threadIdx.x;
  if (r >= NN) return;
  const float4* in4 = (const float4*)(z + (size_t)r * 64);
  for (int c = 0; c < 8; ++c) {
    int c0 = c * 16;
    float acc[16];
#pragma unroll
    for (int j = 0; j < 16; ++j) acc[j] = bl[c0 + j];
    for (int k4 = 0; k4 < 16; ++k4) {
      float4 a = in4[k4];
#pragma unroll
      for (int kk = 0; kk < 4; ++kk) {
        float av = (&a.x)[kk];
#pragma unroll
        for (int j = 0; j < 16; ++j) acc[j] += av * Wl[(k4 * 4 + kk) * 128 + c0 + j];
      }
    }
    float4* out4 = (float4*)(z2 + (size_t)r * 128 + c0);
#pragma unroll
    for (int j4 = 0; j4 < 4; ++j4)
      out4[j4] = make_float4(acc[j4 * 4], acc[j4 * 4 + 1], acc[j4 * 4 + 2], acc[j4 * 4 + 3]);
  }
}

// column sums & sums of squares into stats[0:C], stats[C:2C] (pre-zeroed)
__global__ void k_colstats(const float* __restrict__ src, int C, int total,
                           float* __restrict__ stats) {
  int tid = threadIdx.x;
  float s = 0.f, s2 = 0.f;
  int stride = gridDim.x * TPB;
  for (int idx = blockIdx.x * TPB + tid; idx < total; idx += stride) {
    float v = src[idx];
    s += v;
    s2 += v * v;
  }
  int col = tid & (C - 1);  // valid: C divides TPB and stride
  atomicAdd(&stats[col], s);
  atomicAdd(&stats[C + col], s2);
}

// scale/shift from raw sums: out = v*scale + shift  ==  bn(v)*gamma+beta
__global__ void k_finalize(float* __restrict__ stats, const float* __restrict__ gamma,
                           const float* __restrict__ beta, int C) {
  int c = threadIdx.x;
  if (c >= C) return;
  float invN = 1.0f / NN;
  float mu = stats[c] * invN;
  float var = stats[C + c] * invN - mu * mu;
  float rs = rsqrtf(var + BN_EPS) * gamma[c];
  stats[2 * C + c] = rs;
  stats[3 * C + c] = beta[c] - mu * rs;
}

// h[N,64] = relu( relu(bn(z2)) @ W[128,64] + bias )
__global__ __launch_bounds__(TPB) void k_gemm2(const float* __restrict__ z2,
                                               const float* __restrict__ W,
                                               const float* __restrict__ bias,
                                               const float* __restrict__ scl_g,
                                               const float* __restrict__ sht_g,
                                               float* __restrict__ h) {
  __shared__ float Wl[128 * 64];
  __shared__ float scl[128], sht[128], bl[64];
  for (int t = threadIdx.x; t < 128 * 64 / 4; t += TPB)
    ((float4*)Wl)[t] = ((const float4*)W)[t];
  if (threadIdx.x < 128) {
    scl[threadIdx.x] = scl_g[threadIdx.x];
    sht[threadIdx.x] = sht_g[threadIdx.x];
  }
  if (threadIdx.x < 64) bl[threadIdx.x] = bias[threadIdx.x];
  __syncthreads();
  int r = blockIdx.x * TPB + threadIdx.x;
  if (r >= NN) return;
  const float4* in4 = (const float4*)(z2 + (size_t)r * 128);
  for (int c = 0; c < 4; ++c) {
    int c0 = c * 16;
    float acc[16];
#pragma unroll
    for (int j = 0; j < 16; ++j) acc[j] = bl[c0 + j];
    for (int k4 = 0; k4 < 32; ++k4) {
      float4 a = in4[k4];
#pragma unroll
      for (int kk = 0; kk < 4; ++kk) {
        int k = k4 * 4 + kk;
        float av = fmaxf((&a.x)[kk] * scl[k] + sht[k], 0.f);
#pragma unroll
        for (int j = 0; j < 16; ++j) acc[j] += av * Wl[k * 64 + c0 + j];
      }
    }
    float4* out4 = (float4*)(h + (size_t)r * 64 + c0);
#pragma unroll
    for (int j4 = 0; j4 < 4; ++j4)
      out4[j4] = make_float4(fmaxf(acc[j4 * 4], 0.f), fmaxf(acc[j4 * 4 + 1], 0.f),
                             fmaxf(acc[j4 * 4 + 2], 0.f), fmaxf(acc[j4 * 4 + 3], 0.f));
  }
}

// h = h*scale + shift, elementwise over [NN,64] as float4
__global__ void k_bnapply(float* __restrict__ h, const float* __restrict__ scale,
                          const float* __restrict__ shift) {
  int i = blockIdx.x * TPB + threadIdx.x;
  if (i >= NN * 16) return;
  int c4 = (i & 15) * 4;
  float4 sc = *(const float4*)&scale[c4];
  float4 sh = *(const float4*)&shift[c4];
  float4 v = ((float4*)h)[i];
  v.x = v.x * sc.x + sh.x;
  v.y = v.y * sc.y + sh.y;
  v.z = v.z * sc.z + sh.z;
  v.w = v.w * sc.w + sh.w;
  ((float4*)h)[i] = v;
}

// g[gi] = sum of h rows with batch==gi (batch sorted) ; wave per graph
__global__ void k_poolseg(const float* __restrict__ h, const int* __restrict__ batch,
                          float* __restrict__ g) {
  int wid = (blockIdx.x * TPB + threadIdx.x) >> 6;
  int lane = threadIdx.x & 63;
  if (wid >= NG) return;
  int a = 0, b = NN;
  while (a < b) { int m = (a + b) >> 1; if (batch[m] < wid) a = m + 1; else b = m; }
  int lo = a;
  b = NN;
  while (a < b) { int m = (a + b) >> 1; if (batch[m] < wid + 1) a = m + 1; else b = m; }
  int hi = a;
  float acc = 0.f;
  for (int n = lo; n < hi; ++n) acc += h[n * 64 + lane];
  g[wid * 64 + lane] = acc;
}

// out[512,10] = relu(g @ Wh1 + bh1) @ Wh2 + bh2 ; thread per graph
__global__ void k_head(const float* __restrict__ g, const float* __restrict__ Wh1,
                       const float* __restrict__ bh1, const float* __restrict__ Wh2,
                       const float* __restrict__ bh2, float* __restrict__ out) {
  __shared__ float W1l[64 * 32], W2l[32 * 10], b1l[32], b2l[10];
  for (int t = threadIdx.x; t < 64 * 32; t += TPB) W1l[t] = Wh1[t];
  for (int t = threadIdx.x; t < 320; t += TPB) W2l[t] = Wh2[t];
  if (threadIdx.x < 32) b1l[threadIdx.x] = bh1[threadIdx.x];
  if (threadIdx.x < 10) b2l[threadIdx.x] = bh2[threadIdx.x];
  __syncthreads();
  int gi = blockIdx.x * TPB + threadIdx.x;
  if (gi >= NG) return;
  float hid[32];
#pragma unroll
  for (int j = 0; j < 32; ++j) hid[j] = b1l[j];
  for (int k = 0; k < 64; ++k) {
    float gv = g[gi * 64 + k];
#pragma unroll
    for (int j = 0; j < 32; ++j) hid[j] += gv * W1l[k * 32 + j];
  }
  float o[10];
#pragma unroll
  for (int j = 0; j < 10; ++j) o[j] = b2l[j];
#pragma unroll
  for (int k = 0; k < 32; ++k) {
    float hv = fmaxf(hid[k], 0.f);
#pragma unroll
    for (int j = 0; j < 10; ++j) o[j] += hv * W2l[k * 10 + j];
  }
  for (int j = 0; j < 10; ++j) out[gi * 10 + j] = o[j];
}

extern "C" void kernel_launch(void* const* d_in, const int* in_sizes, int n_in,
                              void* d_out, int out_size, void* d_ws, size_t ws_size,
                              hipStream_t stream) {
  const int* x = (const int*)d_in[0];
  const int* ei = (const int*)d_in[1];
  const int* batch = (const int*)d_in[2];
  const float* emb = (const float*)d_in[3];
  const float* W1 = (const float*)d_in[4];
  const float* b1 = (const float*)d_in[5];
  const float* g1 = (const float*)d_in[6];
  const float* bt1 = (const float*)d_in[7];
  const float* W2 = (const float*)d_in[8];
  const float* b2 = (const float*)d_in[9];
  const float* gbn = (const float*)d_in[10];
  const float* bbn = (const float*)d_in[11];
  const float* Wh1 = (const float*)d_in[12];
  const float* bh1 = (const float*)d_in[13];
  const float* Wh2 = (const float*)d_in[14];
  const float* bh2 = (const float*)d_in[15];
  float* out = (float*)d_out;

  const int* e_src = ei;
  const int* e_dst = ei + NE;

  char* ws = (char*)d_ws;
  size_t off = 0;
  auto alloc = [&](size_t bytes) -> void* {
    void* p = ws + off;
    off = (off + bytes + 255) & ~(size_t)255;
    return p;
  };
  float* h = (float*)alloc((size_t)NN * 64 * 4);
  float* z = (float*)alloc((size_t)NN * 64 * 4);
  float* z2 = (float*)alloc((size_t)NN * 128 * 4);
  int* srcs = (int*)alloc((size_t)NE * 4);
  int* row_ptr = (int*)alloc((size_t)(NN + 1) * 4);
  int* incl = (int*)alloc((size_t)NN * 4);
  int* btot = (int*)alloc(256 * 4);
  float* g = (float*)alloc((size_t)NG * 64 * 4);
  // zero-needed region (contiguous from here):
  size_t zero_begin = off;
  int* counts = (int*)alloc((size_t)NN * 4);
  int* fill_pos = (int*)alloc((size_t)NN * 4);
  float* statsL = (float*)alloc(4 * 512 * 4);  // per layer: [sum128|sq128|scale128|shift128]
  float* statsH = (float*)alloc(3 * 256 * 4);  // per layer: [sum64|sq64|scale64|shift64]
  size_t zero_end = off;
  int zero_words = (int)((zero_end - zero_begin) / 4);
  float* zero_base = (float*)(ws + zero_begin);

  int gz = (zero_words + TPB - 1) / TPB;
  hipLaunchKernelGGL(k_zero, dim3(gz), dim3(TPB), 0, stream, zero_base, zero_words);

  int gE16 = (NN * 16 + TPB - 1) / TPB;   // 3125
  hipLaunchKernelGGL(k_embed, dim3(gE16), dim3(TPB), 0, stream, x, emb, h);

  int gEdge = (NE + TPB - 1) / TPB;       // 3125
  hipLaunchKernelGGL(k_hist, dim3(gEdge), dim3(TPB), 0, stream, e_dst, counts);

  int nScanBlocks = (NN + TPB - 1) / TPB; // 196
  hipLaunchKernelGGL(k_scan1, dim3(nScanBlocks), dim3(TPB), 0, stream, counts, incl, btot);
  hipLaunchKernelGGL(k_scan2, dim3(1), dim3(TPB), 0, stream, btot, nScanBlocks);
  int gScan3 = (NN + 1 + TPB - 1) / TPB;
  hipLaunchKernelGGL(k_scan3, dim3(gScan3), dim3(TPB), 0, stream, incl, btot, row_ptr);
  hipLaunchKernelGGL(k_fill, dim3(gEdge), dim3(TPB), 0, stream, e_src, e_dst, row_ptr,
                     fill_pos, srcs);

  int gAgg = (NN * 64 + TPB - 1) / TPB;   // 12500
  int gRow = (NN + TPB - 1) / TPB;        // 196
  int gStats = 1024;

  for (int i = 0; i < 4; ++i) {
    const float* W1i = W1 + (size_t)i * 64 * 128;
    const float* b1i = b1 + (size_t)i * 128;
    const float* g1i = g1 + (size_t)i * 128;
    const float* bt1i = bt1 + (size_t)i * 128;
    const float* W2i = W2 + (size_t)i * 128 * 64;
    const float* b2i = b2 + (size_t)i * 64;
    float* stL = statsL + (size_t)i * 512;

    hipLaunchKernelGGL(k_aggregate, dim3(gAgg), dim3(TPB), 0, stream, h, row_ptr, srcs, z);
    hipLaunchKernelGGL(k_gemm1, dim3(gRow), dim3(TPB), 0, stream, z, W1i, b1i, z2);
    hipLaunchKernelGGL(k_colstats, dim3(gStats), dim3(TPB), 0, stream, z2, 128, NN * 128, stL);
    hipLaunchKernelGGL(k_finalize, dim3(1), dim3(128), 0, stream, stL, g1i, bt1i, 128);
    hipLaunchKernelGGL(k_gemm2, dim3(gRow), dim3(TPB), 0, stream, z2, W2i, b2i,
                       stL + 256, stL + 384, h);
    if (i < 3) {
      float* stH = statsH + (size_t)i * 256;
      const float* gbni = gbn + (size_t)i * 64;
      const float* bbni = bbn + (size_t)i * 64;
      hipLaunchKernelGGL(k_colstats, dim3(gStats), dim3(TPB), 0, stream, h, 64, NN * 64, stH);
      hipLaunchKernelGGL(k_finalize, dim3(1), dim3(128), 0, stream, stH, gbni, bbni, 64);
      hipLaunchKernelGGL(k_bnapply, dim3(gE16), dim3(TPB), 0, stream, h, stH + 128, stH + 192);
    }
  }

  int gPool = (NG * 64 + TPB - 1) / TPB;  // 128
  hipLaunchKernelGGL(k_poolseg, dim3(gPool), dim3(TPB), 0, stream, h, batch, g);
  hipLaunchKernelGGL(k_head, dim3((NG + TPB - 1) / TPB), dim3(TPB), 0, stream, g, Wh1, bh1,
                     Wh2, bh2, out);
}

// Round 2
// 784.163 us; speedup vs baseline: 1.4945x; 1.4945x over previous
//
#include <hip/hip_runtime.h>

#define NN 50000
#define NE 800000
#define NG 512
#define TPB 256
#define NB_STATS 256
#define BN_EPS 1e-5f

__global__ void k_zero(int* __restrict__ p, int n) {
  int i = blockIdx.x * TPB + threadIdx.x;
  if (i < n) p[i] = 0;
}

__global__ void k_hist(const int* __restrict__ dst, int* __restrict__ counts) {
  int e = blockIdx.x * TPB + threadIdx.x;
  if (e < NE) atomicAdd(&counts[dst[e]], 1);
}

// per-block inclusive scan of counts -> incl, block totals -> btot
__global__ void k_scan1(const int* __restrict__ counts, int* __restrict__ incl,
                        int* __restrict__ btot) {
  __shared__ int lds[TPB];
  int i = blockIdx.x * TPB + threadIdx.x;
  int v = (i < NN) ? counts[i] : 0;
  lds[threadIdx.x] = v;
  __syncthreads();
  for (int off = 1; off < TPB; off <<= 1) {
    int t = (threadIdx.x >= off) ? lds[threadIdx.x - off] : 0;
    __syncthreads();
    lds[threadIdx.x] += t;
    __syncthreads();
  }
  if (i < NN) incl[i] = lds[threadIdx.x];
  if (threadIdx.x == TPB - 1) btot[blockIdx.x] = lds[TPB - 1];
}

// exclusive scan of btot in place (nb <= 256, single block)
__global__ void k_scan2(int* __restrict__ btot, int nb) {
  __shared__ int lds[TPB];
  int t = (threadIdx.x < nb) ? btot[threadIdx.x] : 0;
  int own = t;
  lds[threadIdx.x] = t;
  __syncthreads();
  for (int off = 1; off < TPB; off <<= 1) {
    int u = (threadIdx.x >= off) ? lds[threadIdx.x - off] : 0;
    __syncthreads();
    lds[threadIdx.x] += u;
    __syncthreads();
  }
  btot[threadIdx.x] = lds[threadIdx.x] - own;
}

__global__ void k_scan3(const int* __restrict__ incl, const int* __restrict__ btot,
                        int* __restrict__ row_ptr) {
  int i = blockIdx.x * TPB + threadIdx.x;
  if (i == 0) row_ptr[0] = 0;
  if (i < NN) row_ptr[i + 1] = incl[i] + btot[i >> 8];
}

__global__ void k_fill(const int* __restrict__ src, const int* __restrict__ dst,
                       const int* __restrict__ row_ptr, int* __restrict__ fill_pos,
                       int* __restrict__ srcs) {
  int e = blockIdx.x * TPB + threadIdx.x;
  if (e >= NE) return;
  int d = dst[e];
  int pos = row_ptr[d] + atomicAdd(&fill_pos[d], 1);
  srcs[pos] = src[e];
}

// Layer-0 aggregate: h is implicit (emb[x[n]]); emb is 8KB -> L1-hot.
// z[n][c] = emb[x[n]][c] + sum_src emb[x[src]][c]
__global__ void k_aggregate0(const int* __restrict__ x, const float* __restrict__ emb,
                             const int* __restrict__ row_ptr, const int* __restrict__ srcs,
                             float* __restrict__ z) {
  int wid = (blockIdx.x * TPB + threadIdx.x) >> 6;
  int lane = threadIdx.x & 63;
  if (wid >= NN) return;
  int beg = row_ptr[wid], end = row_ptr[wid + 1];
  float acc = emb[x[wid] * 64 + lane];
  int e = beg;
  for (; e + 4 <= end; e += 4) {
    int x0 = x[srcs[e]], x1 = x[srcs[e + 1]], x2 = x[srcs[e + 2]], x3 = x[srcs[e + 3]];
    acc += emb[x0 * 64 + lane] + emb[x1 * 64 + lane] + emb[x2 * 64 + lane] +
           emb[x3 * 64 + lane];
  }
  for (; e < end; ++e) acc += emb[x[srcs[e]] * 64 + lane];
  z[wid * 64 + lane] = acc;
}

// Layers 1..3 aggregate with folded BatchNorm of the previous layer's h:
// bn(h) = sc*h + sh  =>  z = sc*(h_self + sum h_src) + (1+deg)*sh
__global__ void k_aggregate(const float* __restrict__ h, const int* __restrict__ row_ptr,
                            const int* __restrict__ srcs, const float* __restrict__ bnst,
                            float* __restrict__ z) {
  int wid = (blockIdx.x * TPB + threadIdx.x) >> 6;
  int lane = threadIdx.x & 63;
  if (wid >= NN) return;
  int beg = row_ptr[wid], end = row_ptr[wid + 1];
  float acc = h[wid * 64 + lane];
  int e = beg;
  for (; e + 4 <= end; e += 4) {
    int s0 = srcs[e], s1 = srcs[e + 1], s2 = srcs[e + 2], s3 = srcs[e + 3];
    float v0 = h[s0 * 64 + lane], v1 = h[s1 * 64 + lane];
    float v2 = h[s2 * 64 + lane], v3 = h[s3 * 64 + lane];
    acc += v0 + v1 + v2 + v3;
  }
  for (; e < end; ++e) acc += h[srcs[e] * 64 + lane];
  float sc = bnst[lane], sh = bnst[64 + lane];
  z[wid * 64 + lane] = sc * acc + (float)(1 + end - beg) * sh;
}

// z2[N,128] = z[N,64] @ W[64,128] + bias ; row per thread, W in LDS
__global__ __launch_bounds__(TPB) void k_gemm1(const float* __restrict__ z,
                                               const float* __restrict__ W,
                                               const float* __restrict__ bias,
                                               float* __restrict__ z2) {
  __shared__ float Wl[64 * 128];
  __shared__ float bl[128];
  for (int t = threadIdx.x; t < 64 * 128 / 4; t += TPB)
    ((float4*)Wl)[t] = ((const float4*)W)[t];
  if (threadIdx.x < 128) bl[threadIdx.x] = bias[threadIdx.x];
  __syncthreads();
  int r = blockIdx.x * TPB + threadIdx.x;
  if (r >= NN) return;
  const float4* in4 = (const float4*)(z + (size_t)r * 64);
  for (int c = 0; c < 8; ++c) {
    int c0 = c * 16;
    float acc[16];
#pragma unroll
    for (int j = 0; j < 16; ++j) acc[j] = bl[c0 + j];
    for (int k4 = 0; k4 < 16; ++k4) {
      float4 a = in4[k4];
#pragma unroll
      for (int kk = 0; kk < 4; ++kk) {
        float av = (&a.x)[kk];
#pragma unroll
        for (int j = 0; j < 16; ++j) acc[j] += av * Wl[(k4 * 4 + kk) * 128 + c0 + j];
      }
    }
    float4* out4 = (float4*)(z2 + (size_t)r * 128 + c0);
#pragma unroll
    for (int j4 = 0; j4 < 4; ++j4)
      out4[j4] = make_float4(acc[j4 * 4], acc[j4 * 4 + 1], acc[j4 * 4 + 2], acc[j4 * 4 + 3]);
  }
}

// pass 1 of column stats: per-block partial sum / sumsq, NO atomics.
// partials layout: [NB_STATS][2C] = [sum C | sq C]
template <int C>
__global__ __launch_bounds__(TPB) void k_colstats1(const float* __restrict__ src,
                                                   float* __restrict__ partials) {
  const int RPB = TPB / C;
  int col = threadIdx.x & (C - 1);
  int ro = threadIdx.x / C;
  float s = 0.f, s2 = 0.f;
  for (int row = blockIdx.x * RPB + ro; row < NN; row += NB_STATS * RPB) {
    float v = src[(size_t)row * C + col];
    s += v;
    s2 = fmaf(v, v, s2);
  }
  __shared__ float lds[TPB];
  lds[threadIdx.x] = s;
  __syncthreads();
  if (threadIdx.x < C) {
#pragma unroll
    for (int g = 1; g < RPB; ++g) s += lds[threadIdx.x + g * C];
  }
  __syncthreads();
  lds[threadIdx.x] = s2;
  __syncthreads();
  if (threadIdx.x < C) {
#pragma unroll
    for (int g = 1; g < RPB; ++g) s2 += lds[threadIdx.x + g * C];
    partials[blockIdx.x * 2 * C + threadIdx.x] = s;
    partials[blockIdx.x * 2 * C + C + threadIdx.x] = s2;
  }
}

// pass 2: fold partials, emit fused affine: out[0:C]=scale, out[C:2C]=shift
template <int C>
__global__ void k_finalize(const float* __restrict__ partials, const float* __restrict__ gamma,
                           const float* __restrict__ beta, float* __restrict__ out) {
  int c = threadIdx.x;
  if (c >= C) return;
  float s = 0.f, s2 = 0.f;
  for (int b = 0; b < NB_STATS; ++b) {
    s += partials[b * 2 * C + c];
    s2 += partials[b * 2 * C + C + c];
  }
  float invN = 1.0f / NN;
  float mu = s * invN;
  float var = s2 * invN - mu * mu;
  float rs = rsqrtf(var + BN_EPS) * gamma[c];
  out[c] = rs;
  out[C + c] = beta[c] - mu * rs;
}

// h[N,64] = relu( relu(bn(z2)) @ W[128,64] + bias )
__global__ __launch_bounds__(TPB) void k_gemm2(const float* __restrict__ z2,
                                               const float* __restrict__ W,
                                               const float* __restrict__ bias,
                                               const float* __restrict__ bnst,
                                               float* __restrict__ h) {
  __shared__ float Wl[128 * 64];
  __shared__ float scl[128], sht[128], bl[64];
  for (int t = threadIdx.x; t < 128 * 64 / 4; t += TPB)
    ((float4*)Wl)[t] = ((const float4*)W)[t];
  if (threadIdx.x < 128) {
    scl[threadIdx.x] = bnst[threadIdx.x];
    sht[threadIdx.x] = bnst[128 + threadIdx.x];
  }
  if (threadIdx.x < 64) bl[threadIdx.x] = bias[threadIdx.x];
  __syncthreads();
  int r = blockIdx.x * TPB + threadIdx.x;
  if (r >= NN) return;
  const float4* in4 = (const float4*)(z2 + (size_t)r * 128);
  for (int c = 0; c < 4; ++c) {
    int c0 = c * 16;
    float acc[16];
#pragma unroll
    for (int j = 0; j < 16; ++j) acc[j] = bl[c0 + j];
    for (int k4 = 0; k4 < 32; ++k4) {
      float4 a = in4[k4];
#pragma unroll
      for (int kk = 0; kk < 4; ++kk) {
        int k = k4 * 4 + kk;
        float av = fmaxf((&a.x)[kk] * scl[k] + sht[k], 0.f);
#pragma unroll
        for (int j = 0; j < 16; ++j) acc[j] += av * Wl[k * 64 + c0 + j];
      }
    }
    float4* out4 = (float4*)(h + (size_t)r * 64 + c0);
#pragma unroll
    for (int j4 = 0; j4 < 4; ++j4)
      out4[j4] = make_float4(fmaxf(acc[j4 * 4], 0.f), fmaxf(acc[j4 * 4 + 1], 0.f),
                             fmaxf(acc[j4 * 4 + 2], 0.f), fmaxf(acc[j4 * 4 + 3], 0.f));
  }
}

// g[gi] = sum of h rows with batch==gi (batch sorted) ; wave per graph
__global__ void k_poolseg(const float* __restrict__ h, const int* __restrict__ batch,
                          float* __restrict__ g) {
  int wid = (blockIdx.x * TPB + threadIdx.x) >> 6;
  int lane = threadIdx.x & 63;
  if (wid >= NG) return;
  int a = 0, b = NN;
  while (a < b) { int m = (a + b) >> 1; if (batch[m] < wid) a = m + 1; else b = m; }
  int lo = a;
  b = NN;
  while (a < b) { int m = (a + b) >> 1; if (batch[m] < wid + 1) a = m + 1; else b = m; }
  int hi = a;
  float acc = 0.f;
  for (int n = lo; n < hi; ++n) acc += h[n * 64 + lane];
  g[wid * 64 + lane] = acc;
}

// out[512,10] = relu(g @ Wh1 + bh1) @ Wh2 + bh2 ; thread per graph
__global__ void k_head(const float* __restrict__ g, const float* __restrict__ Wh1,
                       const float* __restrict__ bh1, const float* __restrict__ Wh2,
                       const float* __restrict__ bh2, float* __restrict__ out) {
  __shared__ float W1l[64 * 32], W2l[32 * 10], b1l[32], b2l[10];
  for (int t = threadIdx.x; t < 64 * 32; t += TPB) W1l[t] = Wh1[t];
  for (int t = threadIdx.x; t < 320; t += TPB) W2l[t] = Wh2[t];
  if (threadIdx.x < 32) b1l[threadIdx.x] = bh1[threadIdx.x];
  if (threadIdx.x < 10) b2l[threadIdx.x] = bh2[threadIdx.x];
  __syncthreads();
  int gi = blockIdx.x * TPB + threadIdx.x;
  if (gi >= NG) return;
  float hid[32];
#pragma unroll
  for (int j = 0; j < 32; ++j) hid[j] = b1l[j];
  for (int k = 0; k < 64; ++k) {
    float gv = g[gi * 64 + k];
#pragma unroll
    for (int j = 0; j < 32; ++j) hid[j] += gv * W1l[k * 32 + j];
  }
  float o[10];
#pragma unroll
  for (int j = 0; j < 10; ++j) o[j] = b2l[j];
#pragma unroll
  for (int k = 0; k < 32; ++k) {
    float hv = fmaxf(hid[k], 0.f);
#pragma unroll
    for (int j = 0; j < 10; ++j) o[j] += hv * W2l[k * 10 + j];
  }
  for (int j = 0; j < 10; ++j) out[gi * 10 + j] = o[j];
}

extern "C" void kernel_launch(void* const* d_in, const int* in_sizes, int n_in,
                              void* d_out, int out_size, void* d_ws, size_t ws_size,
                              hipStream_t stream) {
  const int* x = (const int*)d_in[0];
  const int* ei = (const int*)d_in[1];
  const int* batch = (const int*)d_in[2];
  const float* emb = (const float*)d_in[3];
  const float* W1 = (const float*)d_in[4];
  const float* b1 = (const float*)d_in[5];
  const float* g1 = (const float*)d_in[6];
  const float* bt1 = (const float*)d_in[7];
  const float* W2 = (const float*)d_in[8];
  const float* b2 = (const float*)d_in[9];
  const float* gbn = (const float*)d_in[10];
  const float* bbn = (const float*)d_in[11];
  const float* Wh1 = (const float*)d_in[12];
  const float* bh1 = (const float*)d_in[13];
  const float* Wh2 = (const float*)d_in[14];
  const float* bh2 = (const float*)d_in[15];
  float* out = (float*)d_out;

  const int* e_src = ei;
  const int* e_dst = ei + NE;

  char* ws = (char*)d_ws;
  size_t off = 0;
  auto alloc = [&](size_t bytes) -> void* {
    void* p = ws + off;
    off = (off + bytes + 255) & ~(size_t)255;
    return p;
  };
  float* h = (float*)alloc((size_t)NN * 64 * 4);
  float* z = (float*)alloc((size_t)NN * 64 * 4);
  float* z2 = (float*)alloc((size_t)NN * 128 * 4);
  int* srcs = (int*)alloc((size_t)NE * 4);
  int* row_ptr = (int*)alloc((size_t)(NN + 1) * 4);
  int* incl = (int*)alloc((size_t)NN * 4);
  int* btot = (int*)alloc(256 * 4);
  float* g = (float*)alloc((size_t)NG * 64 * 4);
  float* partials = (float*)alloc((size_t)NB_STATS * 256 * 4);
  float* statsL = (float*)alloc(4 * 256 * 4);  // per layer: [scale128|shift128]
  float* statsH = (float*)alloc(3 * 128 * 4);  // per layer: [scale64|shift64]
  // zero-needed region (contiguous padded span counts..fill_pos end):
  int* counts = (int*)alloc((size_t)NN * 4);
  int* fill_pos = (int*)alloc((size_t)NN * 4);
  int zero_words = (int)(((char*)fill_pos - (char*)counts) / 4) + NN;

  int gz = (zero_words + TPB - 1) / TPB;
  k_zero<<<gz, TPB, 0, stream>>>(counts, zero_words);

  int gEdge = (NE + TPB - 1) / TPB;       // 3125
  k_hist<<<gEdge, TPB, 0, stream>>>(e_dst, counts);

  int nScanBlocks = (NN + TPB - 1) / TPB; // 196
  k_scan1<<<nScanBlocks, TPB, 0, stream>>>(counts, incl, btot);
  k_scan2<<<1, TPB, 0, stream>>>(btot, nScanBlocks);
  int gScan3 = (NN + 1 + TPB - 1) / TPB;
  k_scan3<<<gScan3, TPB, 0, stream>>>(incl, btot, row_ptr);
  k_fill<<<gEdge, TPB, 0, stream>>>(e_src, e_dst, row_ptr, fill_pos, srcs);

  int gAgg = (NN * 64 + TPB - 1) / TPB;   // 12500
  int gRow = (NN + TPB - 1) / TPB;        // 196

  for (int i = 0; i < 4; ++i) {
    const float* W1i = W1 + (size_t)i * 64 * 128;
    const float* b1i = b1 + (size_t)i * 128;
    const float* g1i = g1 + (size_t)i * 128;
    const float* bt1i = bt1 + (size_t)i * 128;
    const float* W2i = W2 + (size_t)i * 128 * 64;
    const float* b2i = b2 + (size_t)i * 64;
    float* stL = statsL + (size_t)i * 256;

    if (i == 0)
      k_aggregate0<<<gAgg, TPB, 0, stream>>>(x, emb, row_ptr, srcs, z);
    else
      k_aggregate<<<gAgg, TPB, 0, stream>>>(h, row_ptr, srcs, statsH + (size_t)(i - 1) * 128, z);

    k_gemm1<<<gRow, TPB, 0, stream>>>(z, W1i, b1i, z2);
    k_colstats1<128><<<NB_STATS, TPB, 0, stream>>>(z2, partials);
    k_finalize<128><<<1, 128, 0, stream>>>(partials, g1i, bt1i, stL);
    k_gemm2<<<gRow, TPB, 0, stream>>>(z2, W2i, b2i, stL, h);

    if (i < 3) {
      float* stH = statsH + (size_t)i * 128;
      k_colstats1<64><<<NB_STATS, TPB, 0, stream>>>(h, partials);
      k_finalize<64><<<1, 64, 0, stream>>>(partials, gbn + (size_t)i * 64,
                                           bbn + (size_t)i * 64, stH);
    }
  }

  int gPool = (NG * 64 + TPB - 1) / TPB;  // 128
  k_poolseg<<<gPool, TPB, 0, stream>>>(h, batch, g);
  k_head<<<(NG + TPB - 1) / TPB, TPB, 0, stream>>>(g, Wh1, bh1, Wh2, bh2, out);
}

// Round 3
// 622.437 us; speedup vs baseline: 1.8828x; 1.2598x over previous
//
#include <hip/hip_runtime.h>

#define NN 50000
#define NE 800000
#define NG 512
#define TPB 256
#define BN_EPS 1e-5f
#define GEMM_NBLK 782  // ceil(NN/64)

__global__ void k_zero(int* __restrict__ p, int n) {
  int i = blockIdx.x * TPB + threadIdx.x;
  if (i < n) p[i] = 0;
}

__global__ void k_hist(const int* __restrict__ dst, int* __restrict__ counts) {
  int e = blockIdx.x * TPB + threadIdx.x;
  if (e < NE) atomicAdd(&counts[dst[e]], 1);
}

// per-block inclusive scan of counts -> incl, block totals -> btot
__global__ void k_scan1(const int* __restrict__ counts, int* __restrict__ incl,
                        int* __restrict__ btot) {
  __shared__ int lds[TPB];
  int i = blockIdx.x * TPB + threadIdx.x;
  int v = (i < NN) ? counts[i] : 0;
  lds[threadIdx.x] = v;
  __syncthreads();
  for (int off = 1; off < TPB; off <<= 1) {
    int t = (threadIdx.x >= off) ? lds[threadIdx.x - off] : 0;
    __syncthreads();
    lds[threadIdx.x] += t;
    __syncthreads();
  }
  if (i < NN) incl[i] = lds[threadIdx.x];
  if (threadIdx.x == TPB - 1) btot[blockIdx.x] = lds[TPB - 1];
}

__global__ void k_scan2(int* __restrict__ btot, int nb) {
  __shared__ int lds[TPB];
  int t = (threadIdx.x < nb) ? btot[threadIdx.x] : 0;
  int own = t;
  lds[threadIdx.x] = t;
  __syncthreads();
  for (int off = 1; off < TPB; off <<= 1) {
    int u = (threadIdx.x >= off) ? lds[threadIdx.x - off] : 0;
    __syncthreads();
    lds[threadIdx.x] += u;
    __syncthreads();
  }
  btot[threadIdx.x] = lds[threadIdx.x] - own;
}

__global__ void k_scan3(const int* __restrict__ incl, const int* __restrict__ btot,
                        int* __restrict__ row_ptr) {
  int i = blockIdx.x * TPB + threadIdx.x;
  if (i == 0) row_ptr[0] = 0;
  if (i < NN) row_ptr[i + 1] = incl[i] + btot[i >> 8];
}

__global__ void k_fill(const int* __restrict__ src, const int* __restrict__ dst,
                       const int* __restrict__ row_ptr, int* __restrict__ fill_pos,
                       int* __restrict__ srcs) {
  int e = blockIdx.x * TPB + threadIdx.x;
  if (e >= NE) return;
  int d = dst[e];
  int pos = row_ptr[d] + atomicAdd(&fill_pos[d], 1);
  srcs[pos] = src[e];
}

// Layer-0 aggregate: h implicit = emb[x[n]] (emb is 8KB -> L1-hot)
__global__ void k_aggregate0(const int* __restrict__ x, const float* __restrict__ emb,
                             const int* __restrict__ row_ptr, const int* __restrict__ srcs,
                             float* __restrict__ z) {
  int wid = (blockIdx.x * TPB + threadIdx.x) >> 6;
  int lane = threadIdx.x & 63;
  if (wid >= NN) return;
  int beg = row_ptr[wid], end = row_ptr[wid + 1];
  float acc = emb[x[wid] * 64 + lane];
  int e = beg;
  for (; e + 4 <= end; e += 4) {
    int x0 = x[srcs[e]], x1 = x[srcs[e + 1]], x2 = x[srcs[e + 2]], x3 = x[srcs[e + 3]];
    acc += emb[x0 * 64 + lane] + emb[x1 * 64 + lane] + emb[x2 * 64 + lane] +
           emb[x3 * 64 + lane];
  }
  for (; e < end; ++e) acc += emb[x[srcs[e]] * 64 + lane];
  z[wid * 64 + lane] = acc;
}

// Layers 1..3 aggregate with folded BatchNorm of the previous layer's h:
// bn(h) = sc*h + sh  =>  z = sc*(h_self + sum h_src) + (1+deg)*sh
__global__ void k_aggregate(const float* __restrict__ h, const int* __restrict__ row_ptr,
                            const int* __restrict__ srcs, const float* __restrict__ bnst,
                            float* __restrict__ z) {
  int wid = (blockIdx.x * TPB + threadIdx.x) >> 6;
  int lane = threadIdx.x & 63;
  if (wid >= NN) return;
  int beg = row_ptr[wid], end = row_ptr[wid + 1];
  float acc = h[wid * 64 + lane];
  int e = beg;
  for (; e + 4 <= end; e += 4) {
    int s0 = srcs[e], s1 = srcs[e + 1], s2 = srcs[e + 2], s3 = srcs[e + 3];
    float v0 = h[s0 * 64 + lane], v1 = h[s1 * 64 + lane];
    float v2 = h[s2 * 64 + lane], v3 = h[s3 * 64 + lane];
    acc += v0 + v1 + v2 + v3;
  }
  for (; e < end; ++e) acc += h[srcs[e] * 64 + lane];
  float sc = bnst[lane], sh = bnst[64 + lane];
  z[wid * 64 + lane] = sc * acc + (float)(1 + end - beg) * sh;
}

// Tiled GEMM: out[N,NC] = f(in[N,K]) @ W[K,NC] + bias, 64 rows/block, 256 thr.
// IN_BN: in-transform relu(in*scale+shift) (scale=bnst[0:K], shift=bnst[K:2K])
// OUT_RELU: relu on output. STATS: per-block column sum/sumsq partials of the
// (post-transform) stored output, for the following BatchNorm.
template <int K, int NC, bool IN_BN, bool OUT_RELU, bool STATS>
__global__ __launch_bounds__(TPB) void k_gemm(const float* __restrict__ in,
                                              const float* __restrict__ W,
                                              const float* __restrict__ bias,
                                              const float* __restrict__ bnst,
                                              float* __restrict__ outp,
                                              float* __restrict__ partials) {
  constexpr int TX = NC / 4;    // threads across cols (32 / 16)
  constexpr int TY = TPB / TX;  // row groups (8 / 16)
  constexpr int RT = 64 / TY;   // rows per thread (8 / 4)
  constexpr int LDA = (K == 64) ? 68 : 128;
  __shared__ float Al[64 * LDA];
  __shared__ float Wl[K * NC];
  const int t = threadIdx.x;
  const int r0 = blockIdx.x * 64;

  // stage W (K*NC = 8192 floats both shapes)
  {
    const float4* Wg = (const float4*)W;
    float4* Wl4 = (float4*)Wl;
#pragma unroll
    for (int j = 0; j < (K * NC / 4) / TPB; ++j) Wl4[t + j * TPB] = Wg[t + j * TPB];
  }
  // stage A
  if constexpr (K == 64) {
#pragma unroll
    for (int j = 0; j < 4; ++j) {
      int qi = t + j * TPB;
      int row = qi >> 4, cq = qi & 15;
      int r = r0 + row;
      float4 v = make_float4(0.f, 0.f, 0.f, 0.f);
      if (r < NN) v = *(const float4*)&in[(size_t)r * 64 + cq * 4];
      *(float4*)&Al[row * LDA + cq * 4] = v;
    }
  } else {
    int cq = t & 31, rb = t >> 5;
    float4 sc4 = make_float4(0, 0, 0, 0), sh4 = make_float4(0, 0, 0, 0);
    if constexpr (IN_BN) {
      sc4 = *(const float4*)&bnst[cq * 4];
      sh4 = *(const float4*)&bnst[K + cq * 4];
    }
#pragma unroll
    for (int j = 0; j < 8; ++j) {
      int row = rb + j * 8;
      int r = r0 + row;
      float4 v = make_float4(0.f, 0.f, 0.f, 0.f);
      if (r < NN) {
        v = *(const float4*)&in[(size_t)r * 128 + cq * 4];
        if constexpr (IN_BN) {
          v.x = fmaxf(fmaf(v.x, sc4.x, sh4.x), 0.f);
          v.y = fmaxf(fmaf(v.y, sc4.y, sh4.y), 0.f);
          v.z = fmaxf(fmaf(v.z, sc4.z, sh4.z), 0.f);
          v.w = fmaxf(fmaf(v.w, sc4.w, sh4.w), 0.f);
        }
      }
      *(float4*)&Al[row * LDA + cq * 4] = v;
    }
  }
  __syncthreads();

  const int tx = t % TX, ty = t / TX;
  const int c0 = tx * 4;
  float4 b0 = *(const float4*)&bias[c0];
  float acc[RT][4];
#pragma unroll
  for (int i = 0; i < RT; ++i) {
    acc[i][0] = b0.x; acc[i][1] = b0.y; acc[i][2] = b0.z; acc[i][3] = b0.w;
  }
  const float* Ab = &Al[ty * RT * LDA];
#pragma unroll 4
  for (int k4 = 0; k4 < K / 4; ++k4) {
    float4 a[RT];
#pragma unroll
    for (int i = 0; i < RT; ++i) a[i] = *(const float4*)&Ab[i * LDA + k4 * 4];
#pragma unroll
    for (int kk = 0; kk < 4; ++kk) {
      float4 b = *(const float4*)&Wl[(k4 * 4 + kk) * NC + c0];
#pragma unroll
      for (int i = 0; i < RT; ++i) {
        float av = (&a[i].x)[kk];
        acc[i][0] = fmaf(av, b.x, acc[i][0]);
        acc[i][1] = fmaf(av, b.y, acc[i][1]);
        acc[i][2] = fmaf(av, b.z, acc[i][2]);
        acc[i][3] = fmaf(av, b.w, acc[i][3]);
      }
    }
  }
  // epilogue: store (+relu) and per-thread column partials over valid rows
  float s[4] = {0.f, 0.f, 0.f, 0.f}, q[4] = {0.f, 0.f, 0.f, 0.f};
#pragma unroll
  for (int i = 0; i < RT; ++i) {
    int r = r0 + ty * RT + i;
    if (r < NN) {
      float4 o;
      o.x = OUT_RELU ? fmaxf(acc[i][0], 0.f) : acc[i][0];
      o.y = OUT_RELU ? fmaxf(acc[i][1], 0.f) : acc[i][1];
      o.z = OUT_RELU ? fmaxf(acc[i][2], 0.f) : acc[i][2];
      o.w = OUT_RELU ? fmaxf(acc[i][3], 0.f) : acc[i][3];
      *(float4*)&outp[(size_t)r * NC + c0] = o;
      if constexpr (STATS) {
        s[0] += o.x; q[0] += o.x * o.x;
        s[1] += o.y; q[1] += o.y * o.y;
        s[2] += o.z; q[2] += o.z * o.z;
        s[3] += o.w; q[3] += o.w * o.w;
      }
    }
  }
  if constexpr (STATS) {
    __syncthreads();  // done reading Al; reuse as reduction scratch
    float* Sl = Al;   // needs 2*TY*NC = 2048 floats <= 64*LDA  (ok)
#pragma unroll
    for (int j = 0; j < 4; ++j) {
      Sl[ty * NC + c0 + j] = s[j];
      Sl[TY * NC + ty * NC + c0 + j] = q[j];
    }
    __syncthreads();
    if (t < NC) {
      float ss = 0.f, qq = 0.f;
#pragma unroll
      for (int g = 0; g < TY; ++g) {
        ss += Sl[g * NC + t];
        qq += Sl[TY * NC + g * NC + t];
      }
      partials[blockIdx.x * 2 * NC + t] = ss;
      partials[blockIdx.x * 2 * NC + NC + t] = qq;
    }
  }
}

// fold partials across GEMM_NBLK blocks, emit fused affine [scale C | shift C]
template <int C>
__global__ void k_finalize(const float* __restrict__ partials, const float* __restrict__ gamma,
                           const float* __restrict__ beta, float* __restrict__ out) {
  int c = threadIdx.x;
  if (c >= C) return;
  float s = 0.f, s2 = 0.f;
  for (int b = 0; b < GEMM_NBLK; ++b) {
    s += partials[b * 2 * C + c];
    s2 += partials[b * 2 * C + C + c];
  }
  float invN = 1.0f / NN;
  float mu = s * invN;
  float var = s2 * invN - mu * mu;
  float rs = rsqrtf(var + BN_EPS) * gamma[c];
  out[c] = rs;
  out[C + c] = beta[c] - mu * rs;
}

// g[gi] = sum of h rows with batch==gi (batch sorted) ; wave per graph
__global__ void k_poolseg(const float* __restrict__ h, const int* __restrict__ batch,
                          float* __restrict__ g) {
  int wid = (blockIdx.x * TPB + threadIdx.x) >> 6;
  int lane = threadIdx.x & 63;
  if (wid >= NG) return;
  int a = 0, b = NN;
  while (a < b) { int m = (a + b) >> 1; if (batch[m] < wid) a = m + 1; else b = m; }
  int lo = a;
  b = NN;
  while (a < b) { int m = (a + b) >> 1; if (batch[m] < wid + 1) a = m + 1; else b = m; }
  int hi = a;
  float acc = 0.f;
  for (int n = lo; n < hi; ++n) acc += h[n * 64 + lane];
  g[wid * 64 + lane] = acc;
}

// out[512,10] = relu(g @ Wh1 + bh1) @ Wh2 + bh2 ; thread per graph
__global__ void k_head(const float* __restrict__ g, const float* __restrict__ Wh1,
                       const float* __restrict__ bh1, const float* __restrict__ Wh2,
                       const float* __restrict__ bh2, float* __restrict__ out) {
  __shared__ float W1l[64 * 32], W2l[32 * 10], b1l[32], b2l[10];
  for (int t = threadIdx.x; t < 64 * 32; t += TPB) W1l[t] = Wh1[t];
  for (int t = threadIdx.x; t < 320; t += TPB) W2l[t] = Wh2[t];
  if (threadIdx.x < 32) b1l[threadIdx.x] = bh1[threadIdx.x];
  if (threadIdx.x < 10) b2l[threadIdx.x] = bh2[threadIdx.x];
  __syncthreads();
  int gi = blockIdx.x * TPB + threadIdx.x;
  if (gi >= NG) return;
  float hid[32];
#pragma unroll
  for (int j = 0; j < 32; ++j) hid[j] = b1l[j];
  for (int k = 0; k < 64; ++k) {
    float gv = g[gi * 64 + k];
#pragma unroll
    for (int j = 0; j < 32; ++j) hid[j] += gv * W1l[k * 32 + j];
  }
  float o[10];
#pragma unroll
  for (int j = 0; j < 10; ++j) o[j] = b2l[j];
#pragma unroll
  for (int k = 0; k < 32; ++k) {
    float hv = fmaxf(hid[k], 0.f);
#pragma unroll
    for (int j = 0; j < 10; ++j) o[j] += hv * W2l[k * 10 + j];
  }
  for (int j = 0; j < 10; ++j) out[gi * 10 + j] = o[j];
}

extern "C" void kernel_launch(void* const* d_in, const int* in_sizes, int n_in,
                              void* d_out, int out_size, void* d_ws, size_t ws_size,
                              hipStream_t stream) {
  const int* x = (const int*)d_in[0];
  const int* ei = (const int*)d_in[1];
  const int* batch = (const int*)d_in[2];
  const float* emb = (const float*)d_in[3];
  const float* W1 = (const float*)d_in[4];
  const float* b1 = (const float*)d_in[5];
  const float* g1 = (const float*)d_in[6];
  const float* bt1 = (const float*)d_in[7];
  const float* W2 = (const float*)d_in[8];
  const float* b2 = (const float*)d_in[9];
  const float* gbn = (const float*)d_in[10];
  const float* bbn = (const float*)d_in[11];
  const float* Wh1 = (const float*)d_in[12];
  const float* bh1 = (const float*)d_in[13];
  const float* Wh2 = (const float*)d_in[14];
  const float* bh2 = (const float*)d_in[15];
  float* out = (float*)d_out;

  const int* e_src = ei;
  const int* e_dst = ei + NE;

  char* ws = (char*)d_ws;
  size_t off = 0;
  auto alloc = [&](size_t bytes) -> void* {
    void* p = ws + off;
    off = (off + bytes + 255) & ~(size_t)255;
    return p;
  };
  float* h = (float*)alloc((size_t)NN * 64 * 4);
  float* z = (float*)alloc((size_t)NN * 64 * 4);
  float* z2 = (float*)alloc((size_t)NN * 128 * 4);
  int* srcs = (int*)alloc((size_t)NE * 4);
  int* row_ptr = (int*)alloc((size_t)(NN + 1) * 4);
  int* incl = (int*)alloc((size_t)NN * 4);
  int* btot = (int*)alloc(256 * 4);
  float* g = (float*)alloc((size_t)NG * 64 * 4);
  float* partials = (float*)alloc((size_t)GEMM_NBLK * 256 * 4);
  float* statsL = (float*)alloc(4 * 256 * 4);  // per layer: [scale128|shift128]
  float* statsH = (float*)alloc(3 * 128 * 4);  // per layer: [scale64|shift64]
  int* counts = (int*)alloc((size_t)NN * 4);
  int* fill_pos = (int*)alloc((size_t)NN * 4);
  int zero_words = (int)(((char*)fill_pos - (char*)counts) / 4) + NN;

  int gz = (zero_words + TPB - 1) / TPB;
  k_zero<<<gz, TPB, 0, stream>>>(counts, zero_words);

  int gEdge = (NE + TPB - 1) / TPB;
  k_hist<<<gEdge, TPB, 0, stream>>>(e_dst, counts);

  int nScanBlocks = (NN + TPB - 1) / TPB;
  k_scan1<<<nScanBlocks, TPB, 0, stream>>>(counts, incl, btot);
  k_scan2<<<1, TPB, 0, stream>>>(btot, nScanBlocks);
  int gScan3 = (NN + 1 + TPB - 1) / TPB;
  k_scan3<<<gScan3, TPB, 0, stream>>>(incl, btot, row_ptr);
  k_fill<<<gEdge, TPB, 0, stream>>>(e_src, e_dst, row_ptr, fill_pos, srcs);

  int gAgg = (NN * 64 + TPB - 1) / TPB;

  for (int i = 0; i < 4; ++i) {
    const float* W1i = W1 + (size_t)i * 64 * 128;
    const float* b1i = b1 + (size_t)i * 128;
    const float* g1i = g1 + (size_t)i * 128;
    const float* bt1i = bt1 + (size_t)i * 128;
    const float* W2i = W2 + (size_t)i * 128 * 64;
    const float* b2i = b2 + (size_t)i * 64;
    float* stL = statsL + (size_t)i * 256;

    if (i == 0)
      k_aggregate0<<<gAgg, TPB, 0, stream>>>(x, emb, row_ptr, srcs, z);
    else
      k_aggregate<<<gAgg, TPB, 0, stream>>>(h, row_ptr, srcs, statsH + (size_t)(i - 1) * 128, z);

    k_gemm<64, 128, false, false, true>
        <<<GEMM_NBLK, TPB, 0, stream>>>(z, W1i, b1i, nullptr, z2, partials);
    k_finalize<128><<<1, 128, 0, stream>>>(partials, g1i, bt1i, stL);

    if (i < 3) {
      float* stH = statsH + (size_t)i * 128;
      k_gemm<128, 64, true, true, true>
          <<<GEMM_NBLK, TPB, 0, stream>>>(z2, W2i, b2i, stL, h, partials);
      k_finalize<64><<<1, 64, 0, stream>>>(partials, gbn + (size_t)i * 64,
                                           bbn + (size_t)i * 64, stH);
    } else {
      k_gemm<128, 64, true, true, false>
          <<<GEMM_NBLK, TPB, 0, stream>>>(z2, W2i, b2i, stL, h, partials);
    }
  }

  int gPool = (NG * 64 + TPB - 1) / TPB;
  k_poolseg<<<gPool, TPB, 0, stream>>>(h, batch, g);
  k_head<<<(NG + TPB - 1) / TPB, TPB, 0, stream>>>(g, Wh1, bh1, Wh2, bh2, out);
}

// Round 4
// 602.219 us; speedup vs baseline: 1.9460x; 1.0336x over previous
//
#include <hip/hip_runtime.h>

#define NN 50000
#define NE 800000
#define NG 512
#define TPB 256
#define BN_EPS 1e-5f
#define GEMM_NBLK 782   // ceil(NN/64)
#define EDGE_BLKS 3125  // NE/TPB exactly
#define FILL_P 4
#define FILL_CHUNK 12500  // NN/FILL_P

__global__ void k_zero(int* __restrict__ p, int n) {
  int i = blockIdx.x * TPB + threadIdx.x;
  if (i < n) p[i] = 0;
}

__global__ void k_hist(const int* __restrict__ dst, int* __restrict__ counts) {
  int e = blockIdx.x * TPB + threadIdx.x;
  if (e < NE) atomicAdd(&counts[dst[e]], 1);
}

// per-block inclusive scan of counts -> incl, block totals -> btot
__global__ void k_scan1(const int* __restrict__ counts, int* __restrict__ incl,
                        int* __restrict__ btot) {
  __shared__ int lds[TPB];
  int i = blockIdx.x * TPB + threadIdx.x;
  int v = (i < NN) ? counts[i] : 0;
  lds[threadIdx.x] = v;
  __syncthreads();
  for (int off = 1; off < TPB; off <<= 1) {
    int t = (threadIdx.x >= off) ? lds[threadIdx.x - off] : 0;
    __syncthreads();
    lds[threadIdx.x] += t;
    __syncthreads();
  }
  if (i < NN) incl[i] = lds[threadIdx.x];
  if (threadIdx.x == TPB - 1) btot[blockIdx.x] = lds[TPB - 1];
}

__global__ void k_scan2(int* __restrict__ btot, int nb) {
  __shared__ int lds[TPB];
  int t = (threadIdx.x < nb) ? btot[threadIdx.x] : 0;
  int own = t;
  lds[threadIdx.x] = t;
  __syncthreads();
  for (int off = 1; off < TPB; off <<= 1) {
    int u = (threadIdx.x >= off) ? lds[threadIdx.x - off] : 0;
    __syncthreads();
    lds[threadIdx.x] += u;
    __syncthreads();
  }
  btot[threadIdx.x] = lds[threadIdx.x] - own;
}

__global__ void k_scan3(const int* __restrict__ incl, const int* __restrict__ btot,
                        int* __restrict__ row_ptr) {
  int i = blockIdx.x * TPB + threadIdx.x;
  if (i == 0) row_ptr[0] = 0;
  if (i < NN) row_ptr[i + 1] = incl[i] + btot[i >> 8];
}

// Range-partitioned counting-sort fill: pass p (grid-major) handles edges whose
// dst is in [p*FILL_CHUNK, (p+1)*FILL_CHUNK) so concurrent scatter writes land
// in an ~800KB window (L2-resident -> full-line evictions instead of 16x
// partial-line write amplification).
__global__ void k_fill(const int* __restrict__ src, const int* __restrict__ dst,
                       const int* __restrict__ row_ptr, int* __restrict__ fill_pos,
                       int* __restrict__ srcs) {
  int bid = blockIdx.x;
  int pass = bid / EDGE_BLKS;
  int e = (bid - pass * EDGE_BLKS) * TPB + threadIdx.x;
  int d = dst[e];
  if (d / FILL_CHUNK != pass) return;
  int pos = row_ptr[d] + atomicAdd(&fill_pos[d], 1);
  srcs[pos] = src[e];
}

// Layer-0 aggregate: h implicit = emb[x[n]] (emb is 8KB -> L1-hot)
__global__ void k_aggregate0(const int* __restrict__ x, const float* __restrict__ emb,
                             const int* __restrict__ row_ptr, const int* __restrict__ srcs,
                             float* __restrict__ z) {
  int wid = (blockIdx.x * TPB + threadIdx.x) >> 6;
  int lane = threadIdx.x & 63;
  if (wid >= NN) return;
  int beg = row_ptr[wid], end = row_ptr[wid + 1];
  float acc = emb[x[wid] * 64 + lane];
  int e = beg;
  for (; e + 4 <= end; e += 4) {
    int x0 = x[srcs[e]], x1 = x[srcs[e + 1]], x2 = x[srcs[e + 2]], x3 = x[srcs[e + 3]];
    acc += emb[x0 * 64 + lane] + emb[x1 * 64 + lane] + emb[x2 * 64 + lane] +
           emb[x3 * 64 + lane];
  }
  for (; e < end; ++e) acc += emb[x[srcs[e]] * 64 + lane];
  z[wid * 64 + lane] = acc;
}

// Layers 1..3 aggregate with folded BatchNorm of the previous layer's h:
// bn(h) = sc*h + sh  =>  z = sc*(h_self + sum h_src) + (1+deg)*sh
__global__ void k_aggregate(const float* __restrict__ h, const int* __restrict__ row_ptr,
                            const int* __restrict__ srcs, const float* __restrict__ bnst,
                            float* __restrict__ z) {
  int wid = (blockIdx.x * TPB + threadIdx.x) >> 6;
  int lane = threadIdx.x & 63;
  if (wid >= NN) return;
  int beg = row_ptr[wid], end = row_ptr[wid + 1];
  float acc = h[wid * 64 + lane];
  int e = beg;
  for (; e + 4 <= end; e += 4) {
    int s0 = srcs[e], s1 = srcs[e + 1], s2 = srcs[e + 2], s3 = srcs[e + 3];
    float v0 = h[s0 * 64 + lane], v1 = h[s1 * 64 + lane];
    float v2 = h[s2 * 64 + lane], v3 = h[s3 * 64 + lane];
    acc += v0 + v1 + v2 + v3;
  }
  for (; e < end; ++e) acc += h[srcs[e] * 64 + lane];
  float sc = bnst[lane], sh = bnst[64 + lane];
  z[wid * 64 + lane] = sc * acc + (float)(1 + end - beg) * sh;
}

// Tiled GEMM: out[N,NC] = f(in[N,K]) @ W[K,NC] + bias, 64 rows/block, 256 thr.
template <int K, int NC, bool IN_BN, bool OUT_RELU, bool STATS>
__global__ __launch_bounds__(TPB) void k_gemm(const float* __restrict__ in,
                                              const float* __restrict__ W,
                                              const float* __restrict__ bias,
                                              const float* __restrict__ bnst,
                                              float* __restrict__ outp,
                                              float* __restrict__ partials) {
  constexpr int TX = NC / 4;
  constexpr int TY = TPB / TX;
  constexpr int RT = 64 / TY;
  constexpr int LDA = (K == 64) ? 68 : 128;
  __shared__ float Al[64 * LDA];
  __shared__ float Wl[K * NC];
  const int t = threadIdx.x;
  const int r0 = blockIdx.x * 64;

  {
    const float4* Wg = (const float4*)W;
    float4* Wl4 = (float4*)Wl;
#pragma unroll
    for (int j = 0; j < (K * NC / 4) / TPB; ++j) Wl4[t + j * TPB] = Wg[t + j * TPB];
  }
  if constexpr (K == 64) {
#pragma unroll
    for (int j = 0; j < 4; ++j) {
      int qi = t + j * TPB;
      int row = qi >> 4, cq = qi & 15;
      int r = r0 + row;
      float4 v = make_float4(0.f, 0.f, 0.f, 0.f);
      if (r < NN) v = *(const float4*)&in[(size_t)r * 64 + cq * 4];
      *(float4*)&Al[row * LDA + cq * 4] = v;
    }
  } else {
    int cq = t & 31, rb = t >> 5;
    float4 sc4 = make_float4(0, 0, 0, 0), sh4 = make_float4(0, 0, 0, 0);
    if constexpr (IN_BN) {
      sc4 = *(const float4*)&bnst[cq * 4];
      sh4 = *(const float4*)&bnst[K + cq * 4];
    }
#pragma unroll
    for (int j = 0; j < 8; ++j) {
      int row = rb + j * 8;
      int r = r0 + row;
      float4 v = make_float4(0.f, 0.f, 0.f, 0.f);
      if (r < NN) {
        v = *(const float4*)&in[(size_t)r * 128 + cq * 4];
        if constexpr (IN_BN) {
          v.x = fmaxf(fmaf(v.x, sc4.x, sh4.x), 0.f);
          v.y = fmaxf(fmaf(v.y, sc4.y, sh4.y), 0.f);
          v.z = fmaxf(fmaf(v.z, sc4.z, sh4.z), 0.f);
          v.w = fmaxf(fmaf(v.w, sc4.w, sh4.w), 0.f);
        }
      }
      *(float4*)&Al[row * LDA + cq * 4] = v;
    }
  }
  __syncthreads();

  const int tx = t % TX, ty = t / TX;
  const int c0 = tx * 4;
  float4 b0 = *(const float4*)&bias[c0];
  float acc[RT][4];
#pragma unroll
  for (int i = 0; i < RT; ++i) {
    acc[i][0] = b0.x; acc[i][1] = b0.y; acc[i][2] = b0.z; acc[i][3] = b0.w;
  }
  const float* Ab = &Al[ty * RT * LDA];
#pragma unroll 4
  for (int k4 = 0; k4 < K / 4; ++k4) {
    float4 a[RT];
#pragma unroll
    for (int i = 0; i < RT; ++i) a[i] = *(const float4*)&Ab[i * LDA + k4 * 4];
#pragma unroll
    for (int kk = 0; kk < 4; ++kk) {
      float4 b = *(const float4*)&Wl[(k4 * 4 + kk) * NC + c0];
#pragma unroll
      for (int i = 0; i < RT; ++i) {
        float av = (&a[i].x)[kk];
        acc[i][0] = fmaf(av, b.x, acc[i][0]);
        acc[i][1] = fmaf(av, b.y, acc[i][1]);
        acc[i][2] = fmaf(av, b.z, acc[i][2]);
        acc[i][3] = fmaf(av, b.w, acc[i][3]);
      }
    }
  }
  float s[4] = {0.f, 0.f, 0.f, 0.f}, q[4] = {0.f, 0.f, 0.f, 0.f};
#pragma unroll
  for (int i = 0; i < RT; ++i) {
    int r = r0 + ty * RT + i;
    if (r < NN) {
      float4 o;
      o.x = OUT_RELU ? fmaxf(acc[i][0], 0.f) : acc[i][0];
      o.y = OUT_RELU ? fmaxf(acc[i][1], 0.f) : acc[i][1];
      o.z = OUT_RELU ? fmaxf(acc[i][2], 0.f) : acc[i][2];
      o.w = OUT_RELU ? fmaxf(acc[i][3], 0.f) : acc[i][3];
      *(float4*)&outp[(size_t)r * NC + c0] = o;
      if constexpr (STATS) {
        s[0] += o.x; q[0] += o.x * o.x;
        s[1] += o.y; q[1] += o.y * o.y;
        s[2] += o.z; q[2] += o.z * o.z;
        s[3] += o.w; q[3] += o.w * o.w;
      }
    }
  }
  if constexpr (STATS) {
    __syncthreads();
    float* Sl = Al;
#pragma unroll
    for (int j = 0; j < 4; ++j) {
      Sl[ty * NC + c0 + j] = s[j];
      Sl[TY * NC + ty * NC + c0 + j] = q[j];
    }
    __syncthreads();
    if (t < NC) {
      float ss = 0.f, qq = 0.f;
#pragma unroll
      for (int g = 0; g < TY; ++g) {
        ss += Sl[g * NC + t];
        qq += Sl[TY * NC + g * NC + t];
      }
      partials[blockIdx.x * 2 * NC + t] = ss;
      partials[blockIdx.x * 2 * NC + NC + t] = qq;
    }
  }
}

template <int C>
__global__ void k_finalize(const float* __restrict__ partials, const float* __restrict__ gamma,
                           const float* __restrict__ beta, float* __restrict__ out) {
  int c = threadIdx.x;
  if (c >= C) return;
  float s = 0.f, s2 = 0.f;
  for (int b = 0; b < GEMM_NBLK; ++b) {
    s += partials[b * 2 * C + c];
    s2 += partials[b * 2 * C + C + c];
  }
  float invN = 1.0f / NN;
  float mu = s * invN;
  float var = s2 * invN - mu * mu;
  float rs = rsqrtf(var + BN_EPS) * gamma[c];
  out[c] = rs;
  out[C + c] = beta[c] - mu * rs;
}

// one BLOCK per graph: 4 waves stride the (sorted, contiguous) row range,
// LDS-reduce the 4 partials.
__global__ void k_poolseg(const float* __restrict__ h, const int* __restrict__ batch,
                          float* __restrict__ g) {
  __shared__ float lds[TPB];
  int gi = blockIdx.x;
  int lane = threadIdx.x & 63, w = threadIdx.x >> 6;
  int a = 0, b = NN;
  while (a < b) { int m = (a + b) >> 1; if (batch[m] < gi) a = m + 1; else b = m; }
  int lo = a;
  b = NN;
  while (a < b) { int m = (a + b) >> 1; if (batch[m] < gi + 1) a = m + 1; else b = m; }
  int hi = a;
  float acc = 0.f;
  for (int n = lo + w; n < hi; n += 4) acc += h[(size_t)n * 64 + lane];
  lds[threadIdx.x] = acc;
  __syncthreads();
  if (w == 0)
    g[gi * 64 + lane] = lds[lane] + lds[64 + lane] + lds[128 + lane] + lds[192 + lane];
}

// out[512,10] = relu(g @ Wh1 + bh1) @ Wh2 + bh2 ; thread per graph
__global__ void k_head(const float* __restrict__ g, const float* __restrict__ Wh1,
                       const float* __restrict__ bh1, const float* __restrict__ Wh2,
                       const float* __restrict__ bh2, float* __restrict__ out) {
  __shared__ float W1l[64 * 32], W2l[32 * 10], b1l[32], b2l[10];
  for (int t = threadIdx.x; t < 64 * 32; t += TPB) W1l[t] = Wh1[t];
  for (int t = threadIdx.x; t < 320; t += TPB) W2l[t] = Wh2[t];
  if (threadIdx.x < 32) b1l[threadIdx.x] = bh1[threadIdx.x];
  if (threadIdx.x < 10) b2l[threadIdx.x] = bh2[threadIdx.x];
  __syncthreads();
  int gi = blockIdx.x * TPB + threadIdx.x;
  if (gi >= NG) return;
  float hid[32];
#pragma unroll
  for (int j = 0; j < 32; ++j) hid[j] = b1l[j];
  for (int k = 0; k < 64; ++k) {
    float gv = g[gi * 64 + k];
#pragma unroll
    for (int j = 0; j < 32; ++j) hid[j] += gv * W1l[k * 32 + j];
  }
  float o[10];
#pragma unroll
  for (int j = 0; j < 10; ++j) o[j] = b2l[j];
#pragma unroll
  for (int k = 0; k < 32; ++k) {
    float hv = fmaxf(hid[k], 0.f);
#pragma unroll
    for (int j = 0; j < 10; ++j) o[j] += hv * W2l[k * 10 + j];
  }
  for (int j = 0; j < 10; ++j) out[gi * 10 + j] = o[j];
}

extern "C" void kernel_launch(void* const* d_in, const int* in_sizes, int n_in,
                              void* d_out, int out_size, void* d_ws, size_t ws_size,
                              hipStream_t stream) {
  const int* x = (const int*)d_in[0];
  const int* ei = (const int*)d_in[1];
  const int* batch = (const int*)d_in[2];
  const float* emb = (const float*)d_in[3];
  const float* W1 = (const float*)d_in[4];
  const float* b1 = (const float*)d_in[5];
  const float* g1 = (const float*)d_in[6];
  const float* bt1 = (const float*)d_in[7];
  const float* W2 = (const float*)d_in[8];
  const float* b2 = (const float*)d_in[9];
  const float* gbn = (const float*)d_in[10];
  const float* bbn = (const float*)d_in[11];
  const float* Wh1 = (const float*)d_in[12];
  const float* bh1 = (const float*)d_in[13];
  const float* Wh2 = (const float*)d_in[14];
  const float* bh2 = (const float*)d_in[15];
  float* out = (float*)d_out;

  const int* e_src = ei;
  const int* e_dst = ei + NE;

  char* ws = (char*)d_ws;
  size_t off = 0;
  auto alloc = [&](size_t bytes) -> void* {
    void* p = ws + off;
    off = (off + bytes + 255) & ~(size_t)255;
    return p;
  };
  float* h = (float*)alloc((size_t)NN * 64 * 4);
  float* z = (float*)alloc((size_t)NN * 64 * 4);
  float* z2 = (float*)alloc((size_t)NN * 128 * 4);
  int* srcs = (int*)alloc((size_t)NE * 4);
  int* row_ptr = (int*)alloc((size_t)(NN + 1) * 4);
  int* incl = (int*)alloc((size_t)NN * 4);
  int* btot = (int*)alloc(256 * 4);
  float* g = (float*)alloc((size_t)NG * 64 * 4);
  float* partials = (float*)alloc((size_t)GEMM_NBLK * 256 * 4);
  float* statsL = (float*)alloc(4 * 256 * 4);
  float* statsH = (float*)alloc(3 * 128 * 4);
  int* counts = (int*)alloc((size_t)NN * 4);
  int* fill_pos = (int*)alloc((size_t)NN * 4);
  int zero_words = (int)(((char*)fill_pos - (char*)counts) / 4) + NN;

  int gz = (zero_words + TPB - 1) / TPB;
  k_zero<<<gz, TPB, 0, stream>>>(counts, zero_words);

  k_hist<<<EDGE_BLKS, TPB, 0, stream>>>(e_dst, counts);

  int nScanBlocks = (NN + TPB - 1) / TPB;
  k_scan1<<<nScanBlocks, TPB, 0, stream>>>(counts, incl, btot);
  k_scan2<<<1, TPB, 0, stream>>>(btot, nScanBlocks);
  int gScan3 = (NN + 1 + TPB - 1) / TPB;
  k_scan3<<<gScan3, TPB, 0, stream>>>(incl, btot, row_ptr);
  k_fill<<<FILL_P * EDGE_BLKS, TPB, 0, stream>>>(e_src, e_dst, row_ptr, fill_pos, srcs);

  int gAgg = (NN * 64 + TPB - 1) / TPB;

  for (int i = 0; i < 4; ++i) {
    const float* W1i = W1 + (size_t)i * 64 * 128;
    const float* b1i = b1 + (size_t)i * 128;
    const float* g1i = g1 + (size_t)i * 128;
    const float* bt1i = bt1 + (size_t)i * 128;
    const float* W2i = W2 + (size_t)i * 128 * 64;
    const float* b2i = b2 + (size_t)i * 64;
    float* stL = statsL + (size_t)i * 256;

    if (i == 0)
      k_aggregate0<<<gAgg, TPB, 0, stream>>>(x, emb, row_ptr, srcs, z);
    else
      k_aggregate<<<gAgg, TPB, 0, stream>>>(h, row_ptr, srcs, statsH + (size_t)(i - 1) * 128, z);

    k_gemm<64, 128, false, false, true>
        <<<GEMM_NBLK, TPB, 0, stream>>>(z, W1i, b1i, nullptr, z2, partials);
    k_finalize<128><<<1, 128, 0, stream>>>(partials, g1i, bt1i, stL);

    if (i < 3) {
      float* stH = statsH + (size_t)i * 128;
      k_gemm<128, 64, true, true, true>
          <<<GEMM_NBLK, TPB, 0, stream>>>(z2, W2i, b2i, stL, h, partials);
      k_finalize<64><<<1, 64, 0, stream>>>(partials, gbn + (size_t)i * 64,
                                           bbn + (size_t)i * 64, stH);
    } else {
      k_gemm<128, 64, true, true, false>
          <<<GEMM_NBLK, TPB, 0, stream>>>(z2, W2i, b2i, stL, h, partials);
    }
  }

  k_poolseg<<<NG, TPB, 0, stream>>>(h, batch, g);
  k_head<<<(NG + TPB - 1) / TPB, TPB, 0, stream>>>(g, Wh1, bh1, Wh2, bh2, out);
}

// Round 5
// 599.563 us; speedup vs baseline: 1.9546x; 1.0044x over previous
//
#include <hip/hip_runtime.h>

#define NN 50000
#define NE 800000
#define NG 512
#define TPB 256
#define BN_EPS 1e-5f
#define GEMM_NBLK 782   // ceil(NN/64)
#define EDGE_BLKS 3125  // NE/TPB exactly
#define FILL_P 8
#define FILL_CHUNK 6250  // NN/FILL_P

__global__ void k_zero(int* __restrict__ p, int n) {
  int i = blockIdx.x * TPB + threadIdx.x;
  if (i < n) p[i] = 0;
}

__global__ void k_hist(const int* __restrict__ dst, int* __restrict__ counts) {
  int e = blockIdx.x * TPB + threadIdx.x;
  if (e < NE) atomicAdd(&counts[dst[e]], 1);
}

// per-block inclusive scan of counts -> incl, block totals -> btot
__global__ void k_scan1(const int* __restrict__ counts, int* __restrict__ incl,
                        int* __restrict__ btot) {
  __shared__ int lds[TPB];
  int i = blockIdx.x * TPB + threadIdx.x;
  int v = (i < NN) ? counts[i] : 0;
  lds[threadIdx.x] = v;
  __syncthreads();
  for (int off = 1; off < TPB; off <<= 1) {
    int t = (threadIdx.x >= off) ? lds[threadIdx.x - off] : 0;
    __syncthreads();
    lds[threadIdx.x] += t;
    __syncthreads();
  }
  if (i < NN) incl[i] = lds[threadIdx.x];
  if (threadIdx.x == TPB - 1) btot[blockIdx.x] = lds[TPB - 1];
}

__global__ void k_scan2(int* __restrict__ btot, int nb) {
  __shared__ int lds[TPB];
  int t = (threadIdx.x < nb) ? btot[threadIdx.x] : 0;
  int own = t;
  lds[threadIdx.x] = t;
  __syncthreads();
  for (int off = 1; off < TPB; off <<= 1) {
    int u = (threadIdx.x >= off) ? lds[threadIdx.x - off] : 0;
    __syncthreads();
    lds[threadIdx.x] += u;
    __syncthreads();
  }
  btot[threadIdx.x] = lds[threadIdx.x] - own;
}

__global__ void k_scan3(const int* __restrict__ incl, const int* __restrict__ btot,
                        int* __restrict__ row_ptr) {
  int i = blockIdx.x * TPB + threadIdx.x;
  if (i == 0) row_ptr[0] = 0;
  if (i < NN) row_ptr[i + 1] = incl[i] + btot[i >> 8];
}

// XCD-pinned counting-sort fill: pass = blockIdx&7 == (heuristically) the XCD
// this block runs on, so all scatter writes into window [pass*6250,(pass+1)*6250)
// come from ONE XCD's L2 -> lines become fully dirty in a single cache and
// evict as full lines (fixes the 8-XCD partial-line write amplification that
// kept WRITE_SIZE at 43MB for a 3.2MB buffer).
__global__ void k_fill(const int* __restrict__ src, const int* __restrict__ dst,
                       const int* __restrict__ row_ptr, int* __restrict__ fill_pos,
                       int* __restrict__ srcs) {
  int pass = blockIdx.x & 7;
  int e = (blockIdx.x >> 3) * TPB + threadIdx.x;
  int d = dst[e];
  if (d / FILL_CHUNK != pass) return;
  int pos = row_ptr[d] + atomicAdd(&fill_pos[d], 1);
  srcs[pos] = src[e];
}

// Layer-0 aggregate: h implicit = emb[x[n]] (emb is 8KB -> L1-hot)
__global__ void k_aggregate0(const int* __restrict__ x, const float* __restrict__ emb,
                             const int* __restrict__ row_ptr, const int* __restrict__ srcs,
                             float* __restrict__ z) {
  int wid = (blockIdx.x * TPB + threadIdx.x) >> 6;
  int lane = threadIdx.x & 63;
  if (wid >= NN) return;
  int beg = row_ptr[wid], end = row_ptr[wid + 1];
  float acc = emb[x[wid] * 64 + lane];
  int e = beg;
  for (; e + 4 <= end; e += 4) {
    int x0 = x[srcs[e]], x1 = x[srcs[e + 1]], x2 = x[srcs[e + 2]], x3 = x[srcs[e + 3]];
    acc += emb[x0 * 64 + lane] + emb[x1 * 64 + lane] + emb[x2 * 64 + lane] +
           emb[x3 * 64 + lane];
  }
  for (; e < end; ++e) acc += emb[x[srcs[e]] * 64 + lane];
  z[wid * 64 + lane] = acc;
}

// Layers 1..3 aggregate with folded BatchNorm of the previous layer's h:
// bn(h) = sc*h + sh  =>  z = sc*(h_self + sum h_src) + (1+deg)*sh
// 8-deep gather unroll for memory-level parallelism against ~600cy LLC latency.
__global__ void k_aggregate(const float* __restrict__ h, const int* __restrict__ row_ptr,
                            const int* __restrict__ srcs, const float* __restrict__ bnst,
                            float* __restrict__ z) {
  int wid = (blockIdx.x * TPB + threadIdx.x) >> 6;
  int lane = threadIdx.x & 63;
  if (wid >= NN) return;
  int beg = row_ptr[wid], end = row_ptr[wid + 1];
  float acc = h[wid * 64 + lane];
  int e = beg;
  for (; e + 8 <= end; e += 8) {
    int s0 = srcs[e], s1 = srcs[e + 1], s2 = srcs[e + 2], s3 = srcs[e + 3];
    int s4 = srcs[e + 4], s5 = srcs[e + 5], s6 = srcs[e + 6], s7 = srcs[e + 7];
    float v0 = h[s0 * 64 + lane], v1 = h[s1 * 64 + lane];
    float v2 = h[s2 * 64 + lane], v3 = h[s3 * 64 + lane];
    float v4 = h[s4 * 64 + lane], v5 = h[s5 * 64 + lane];
    float v6 = h[s6 * 64 + lane], v7 = h[s7 * 64 + lane];
    acc += ((v0 + v1) + (v2 + v3)) + ((v4 + v5) + (v6 + v7));
  }
  for (; e < end; ++e) acc += h[srcs[e] * 64 + lane];
  float sc = bnst[lane], sh = bnst[64 + lane];
  z[wid * 64 + lane] = sc * acc + (float)(1 + end - beg) * sh;
}

// Tiled GEMM: out[N,NC] = f(in[N,K]) @ W[K,NC] + bias, 64 rows/block, 256 thr.
template <int K, int NC, bool IN_BN, bool OUT_RELU, bool STATS>
__global__ __launch_bounds__(TPB) void k_gemm(const float* __restrict__ in,
                                              const float* __restrict__ W,
                                              const float* __restrict__ bias,
                                              const float* __restrict__ bnst,
                                              float* __restrict__ outp,
                                              float* __restrict__ partials) {
  constexpr int TX = NC / 4;
  constexpr int TY = TPB / TX;
  constexpr int RT = 64 / TY;
  constexpr int LDA = (K == 64) ? 68 : 128;
  __shared__ float Al[64 * LDA];
  __shared__ float Wl[K * NC];
  const int t = threadIdx.x;
  const int r0 = blockIdx.x * 64;

  {
    const float4* Wg = (const float4*)W;
    float4* Wl4 = (float4*)Wl;
#pragma unroll
    for (int j = 0; j < (K * NC / 4) / TPB; ++j) Wl4[t + j * TPB] = Wg[t + j * TPB];
  }
  if constexpr (K == 64) {
#pragma unroll
    for (int j = 0; j < 4; ++j) {
      int qi = t + j * TPB;
      int row = qi >> 4, cq = qi & 15;
      int r = r0 + row;
      float4 v = make_float4(0.f, 0.f, 0.f, 0.f);
      if (r < NN) v = *(const float4*)&in[(size_t)r * 64 + cq * 4];
      *(float4*)&Al[row * LDA + cq * 4] = v;
    }
  } else {
    int cq = t & 31, rb = t >> 5;
    float4 sc4 = make_float4(0, 0, 0, 0), sh4 = make_float4(0, 0, 0, 0);
    if constexpr (IN_BN) {
      sc4 = *(const float4*)&bnst[cq * 4];
      sh4 = *(const float4*)&bnst[K + cq * 4];
    }
#pragma unroll
    for (int j = 0; j < 8; ++j) {
      int row = rb + j * 8;
      int r = r0 + row;
      float4 v = make_float4(0.f, 0.f, 0.f, 0.f);
      if (r < NN) {
        v = *(const float4*)&in[(size_t)r * 128 + cq * 4];
        if constexpr (IN_BN) {
          v.x = fmaxf(fmaf(v.x, sc4.x, sh4.x), 0.f);
          v.y = fmaxf(fmaf(v.y, sc4.y, sh4.y), 0.f);
          v.z = fmaxf(fmaf(v.z, sc4.z, sh4.z), 0.f);
          v.w = fmaxf(fmaf(v.w, sc4.w, sh4.w), 0.f);
        }
      }
      *(float4*)&Al[row * LDA + cq * 4] = v;
    }
  }
  __syncthreads();

  const int tx = t % TX, ty = t / TX;
  const int c0 = tx * 4;
  float4 b0 = *(const float4*)&bias[c0];
  float acc[RT][4];
#pragma unroll
  for (int i = 0; i < RT; ++i) {
    acc[i][0] = b0.x; acc[i][1] = b0.y; acc[i][2] = b0.z; acc[i][3] = b0.w;
  }
  const float* Ab = &Al[ty * RT * LDA];
#pragma unroll 4
  for (int k4 = 0; k4 < K / 4; ++k4) {
    float4 a[RT];
#pragma unroll
    for (int i = 0; i < RT; ++i) a[i] = *(const float4*)&Ab[i * LDA + k4 * 4];
#pragma unroll
    for (int kk = 0; kk < 4; ++kk) {
      float4 b = *(const float4*)&Wl[(k4 * 4 + kk) * NC + c0];
#pragma unroll
      for (int i = 0; i < RT; ++i) {
        float av = (&a[i].x)[kk];
        acc[i][0] = fmaf(av, b.x, acc[i][0]);
        acc[i][1] = fmaf(av, b.y, acc[i][1]);
        acc[i][2] = fmaf(av, b.z, acc[i][2]);
        acc[i][3] = fmaf(av, b.w, acc[i][3]);
      }
    }
  }
  float s[4] = {0.f, 0.f, 0.f, 0.f}, q[4] = {0.f, 0.f, 0.f, 0.f};
#pragma unroll
  for (int i = 0; i < RT; ++i) {
    int r = r0 + ty * RT + i;
    if (r < NN) {
      float4 o;
      o.x = OUT_RELU ? fmaxf(acc[i][0], 0.f) : acc[i][0];
      o.y = OUT_RELU ? fmaxf(acc[i][1], 0.f) : acc[i][1];
      o.z = OUT_RELU ? fmaxf(acc[i][2], 0.f) : acc[i][2];
      o.w = OUT_RELU ? fmaxf(acc[i][3], 0.f) : acc[i][3];
      *(float4*)&outp[(size_t)r * NC + c0] = o;
      if constexpr (STATS) {
        s[0] += o.x; q[0] += o.x * o.x;
        s[1] += o.y; q[1] += o.y * o.y;
        s[2] += o.z; q[2] += o.z * o.z;
        s[3] += o.w; q[3] += o.w * o.w;
      }
    }
  }
  if constexpr (STATS) {
    __syncthreads();
    float* Sl = Al;
#pragma unroll
    for (int j = 0; j < 4; ++j) {
      Sl[ty * NC + c0 + j] = s[j];
      Sl[TY * NC + ty * NC + c0 + j] = q[j];
    }
    __syncthreads();
    if (t < NC) {
      float ss = 0.f, qq = 0.f;
#pragma unroll
      for (int g = 0; g < TY; ++g) {
        ss += Sl[g * NC + t];
        qq += Sl[TY * NC + g * NC + t];
      }
      partials[blockIdx.x * 2 * NC + t] = ss;
      partials[blockIdx.x * 2 * NC + NC + t] = qq;
    }
  }
}

template <int C>
__global__ void k_finalize(const float* __restrict__ partials, const float* __restrict__ gamma,
                           const float* __restrict__ beta, float* __restrict__ out) {
  int c = threadIdx.x;
  if (c >= C) return;
  float s = 0.f, s2 = 0.f;
  for (int b = 0; b < GEMM_NBLK; ++b) {
    s += partials[b * 2 * C + c];
    s2 += partials[b * 2 * C + C + c];
  }
  float invN = 1.0f / NN;
  float mu = s * invN;
  float var = s2 * invN - mu * mu;
  float rs = rsqrtf(var + BN_EPS) * gamma[c];
  out[c] = rs;
  out[C + c] = beta[c] - mu * rs;
}

// one BLOCK per graph: 4 waves stride the (sorted, contiguous) row range,
// LDS-reduce the 4 partials.
__global__ void k_poolseg(const float* __restrict__ h, const int* __restrict__ batch,
                          float* __restrict__ g) {
  __shared__ float lds[TPB];
  int gi = blockIdx.x;
  int lane = threadIdx.x & 63, w = threadIdx.x >> 6;
  int a = 0, b = NN;
  while (a < b) { int m = (a + b) >> 1; if (batch[m] < gi) a = m + 1; else b = m; }
  int lo = a;
  b = NN;
  while (a < b) { int m = (a + b) >> 1; if (batch[m] < gi + 1) a = m + 1; else b = m; }
  int hi = a;
  float acc = 0.f;
  for (int n = lo + w; n < hi; n += 4) acc += h[(size_t)n * 64 + lane];
  lds[threadIdx.x] = acc;
  __syncthreads();
  if (w == 0)
    g[gi * 64 + lane] = lds[lane] + lds[64 + lane] + lds[128 + lane] + lds[192 + lane];
}

// out[512,10] = relu(g @ Wh1 + bh1) @ Wh2 + bh2 ; thread per graph
__global__ void k_head(const float* __restrict__ g, const float* __restrict__ Wh1,
                       const float* __restrict__ bh1, const float* __restrict__ Wh2,
                       const float* __restrict__ bh2, float* __restrict__ out) {
  __shared__ float W1l[64 * 32], W2l[32 * 10], b1l[32], b2l[10];
  for (int t = threadIdx.x; t < 64 * 32; t += TPB) W1l[t] = Wh1[t];
  for (int t = threadIdx.x; t < 320; t += TPB) W2l[t] = Wh2[t];
  if (threadIdx.x < 32) b1l[threadIdx.x] = bh1[threadIdx.x];
  if (threadIdx.x < 10) b2l[threadIdx.x] = bh2[threadIdx.x];
  __syncthreads();
  int gi = blockIdx.x * TPB + threadIdx.x;
  if (gi >= NG) return;
  float hid[32];
#pragma unroll
  for (int j = 0; j < 32; ++j) hid[j] = b1l[j];
  for (int k = 0; k < 64; ++k) {
    float gv = g[gi * 64 + k];
#pragma unroll
    for (int j = 0; j < 32; ++j) hid[j] += gv * W1l[k * 32 + j];
  }
  float o[10];
#pragma unroll
  for (int j = 0; j < 10; ++j) o[j] = b2l[j];
#pragma unroll
  for (int k = 0; k < 32; ++k) {
    float hv = fmaxf(hid[k], 0.f);
#pragma unroll
    for (int j = 0; j < 10; ++j) o[j] += hv * W2l[k * 10 + j];
  }
  for (int j = 0; j < 10; ++j) out[gi * 10 + j] = o[j];
}

extern "C" void kernel_launch(void* const* d_in, const int* in_sizes, int n_in,
                              void* d_out, int out_size, void* d_ws, size_t ws_size,
                              hipStream_t stream) {
  const int* x = (const int*)d_in[0];
  const int* ei = (const int*)d_in[1];
  const int* batch = (const int*)d_in[2];
  const float* emb = (const float*)d_in[3];
  const float* W1 = (const float*)d_in[4];
  const float* b1 = (const float*)d_in[5];
  const float* g1 = (const float*)d_in[6];
  const float* bt1 = (const float*)d_in[7];
  const float* W2 = (const float*)d_in[8];
  const float* b2 = (const float*)d_in[9];
  const float* gbn = (const float*)d_in[10];
  const float* bbn = (const float*)d_in[11];
  const float* Wh1 = (const float*)d_in[12];
  const float* bh1 = (const float*)d_in[13];
  const float* Wh2 = (const float*)d_in[14];
  const float* bh2 = (const float*)d_in[15];
  float* out = (float*)d_out;

  const int* e_src = ei;
  const int* e_dst = ei + NE;

  char* ws = (char*)d_ws;
  size_t off = 0;
  auto alloc = [&](size_t bytes) -> void* {
    void* p = ws + off;
    off = (off + bytes + 255) & ~(size_t)255;
    return p;
  };
  float* h = (float*)alloc((size_t)NN * 64 * 4);
  float* z = (float*)alloc((size_t)NN * 64 * 4);
  float* z2 = (float*)alloc((size_t)NN * 128 * 4);
  int* srcs = (int*)alloc((size_t)NE * 4);
  int* row_ptr = (int*)alloc((size_t)(NN + 1) * 4);
  int* incl = (int*)alloc((size_t)NN * 4);
  int* btot = (int*)alloc(256 * 4);
  float* g = (float*)alloc((size_t)NG * 64 * 4);
  float* partials = (float*)alloc((size_t)GEMM_NBLK * 256 * 4);
  float* statsL = (float*)alloc(4 * 256 * 4);
  float* statsH = (float*)alloc(3 * 128 * 4);
  int* counts = (int*)alloc((size_t)NN * 4);
  int* fill_pos = (int*)alloc((size_t)NN * 4);
  int zero_words = (int)(((char*)fill_pos - (char*)counts) / 4) + NN;

  int gz = (zero_words + TPB - 1) / TPB;
  k_zero<<<gz, TPB, 0, stream>>>(counts, zero_words);

  k_hist<<<EDGE_BLKS, TPB, 0, stream>>>(e_dst, counts);

  int nScanBlocks = (NN + TPB - 1) / TPB;
  k_scan1<<<nScanBlocks, TPB, 0, stream>>>(counts, incl, btot);
  k_scan2<<<1, TPB, 0, stream>>>(btot, nScanBlocks);
  int gScan3 = (NN + 1 + TPB - 1) / TPB;
  k_scan3<<<gScan3, TPB, 0, stream>>>(incl, btot, row_ptr);
  k_fill<<<FILL_P * EDGE_BLKS, TPB, 0, stream>>>(e_src, e_dst, row_ptr, fill_pos, srcs);

  int gAgg = (NN * 64 + TPB - 1) / TPB;

  for (int i = 0; i < 4; ++i) {
    const float* W1i = W1 + (size_t)i * 64 * 128;
    const float* b1i = b1 + (size_t)i * 128;
    const float* g1i = g1 + (size_t)i * 128;
    const float* bt1i = bt1 + (size_t)i * 128;
    const float* W2i = W2 + (size_t)i * 128 * 64;
    const float* b2i = b2 + (size_t)i * 64;
    float* stL = statsL + (size_t)i * 256;

    if (i == 0)
      k_aggregate0<<<gAgg, TPB, 0, stream>>>(x, emb, row_ptr, srcs, z);
    else
      k_aggregate<<<gAgg, TPB, 0, stream>>>(h, row_ptr, srcs, statsH + (size_t)(i - 1) * 128, z);

    k_gemm<64, 128, false, false, true>
        <<<GEMM_NBLK, TPB, 0, stream>>>(z, W1i, b1i, nullptr, z2, partials);
    k_finalize<128><<<1, 128, 0, stream>>>(partials, g1i, bt1i, stL);

    if (i < 3) {
      float* stH = statsH + (size_t)i * 128;
      k_gemm<128, 64, true, true, true>
          <<<GEMM_NBLK, TPB, 0, stream>>>(z2, W2i, b2i, stL, h, partials);
      k_finalize<64><<<1, 64, 0, stream>>>(partials, gbn + (size_t)i * 64,
                                           bbn + (size_t)i * 64, stH);
    } else {
      k_gemm<128, 64, true, true, false>
          <<<GEMM_NBLK, TPB, 0, stream>>>(z2, W2i, b2i, stL, h, partials);
    }
  }

  k_poolseg<<<NG, TPB, 0, stream>>>(h, batch, g);
  k_head<<<(NG + TPB - 1) / TPB, TPB, 0, stream>>>(g, Wh1, bh1, Wh2, bh2, out);
}